// Round 6
// baseline (761.385 us; speedup 1.0000x reference)
//
#include <hip/hip_runtime.h>
#include <hip/hip_bf16.h>

#define EPSV 1e-5f
#define BCAP 4096

typedef __attribute__((ext_vector_type(8))) short s16x8;
typedef __attribute__((ext_vector_type(4))) float f32x4;

static __device__ __forceinline__ unsigned short f2b(float f) {
    __hip_bfloat16 h = __float2bfloat16(f);
    return *reinterpret_cast<unsigned short*>(&h);
}

// ---------------- bucketed CSR build ----------------
// bucket b = dst>>7 holds nodes [b*128, b*128+128); packed entry = (src<<7)|(dst&127)

__global__ void k_bin(const int* __restrict__ src, const int* __restrict__ dst,
                      int* __restrict__ bcur, unsigned* __restrict__ tmp, int E) {
    int e = blockIdx.x * blockDim.x + threadIdx.x;
    if (e < E) {
        int d = dst[e];
        int b = d >> 7;
        int pos = atomicAdd(&bcur[b], 1);
        tmp[(size_t)b * BCAP + pos] = ((unsigned)src[e] << 7) | (unsigned)(d & 127);
    }
}

// block per bucket: per-node counts via LDS
__global__ void k_bcount(const int* __restrict__ bcur, const unsigned* __restrict__ tmp,
                         int* __restrict__ cnt, int n) {
    __shared__ int lc[128];
    int b = blockIdx.x, t = threadIdx.x;
    if (t < 128) lc[t] = 0;
    __syncthreads();
    int cb = bcur[b];
    const unsigned* tb = tmp + (size_t)b * BCAP;
    for (int i = t; i < cb; i += 256) atomicAdd(&lc[tb[i] & 127], 1);
    __syncthreads();
    int node = b * 128 + t;
    if (t < 128 && node < n) cnt[node] = lc[t];
}

// single block: exclusive scan of NB (<2048) bucket sums
__global__ void k_scanb2(const int* __restrict__ bcur, int* __restrict__ boff, int NB) {
    __shared__ int ls[256];
    int t = threadIdx.x;
    int c = (NB + 255) / 256;
    int base = t * c;
    int myv[8];
    int s = 0;
    for (int i = 0; i < c; i++) {
        int idx = base + i;
        int v = (idx < NB) ? bcur[idx] : 0;
        myv[i] = v;
        s += v;
    }
    ls[t] = s;
    __syncthreads();
    for (int off = 1; off < 256; off <<= 1) {
        int u = (t >= off) ? ls[t - off] : 0;
        __syncthreads();
        ls[t] += u;
        __syncthreads();
    }
    int run = ls[t] - s;
    for (int i = 0; i < c; i++) {
        int idx = base + i;
        if (idx < NB) boff[idx] = run;
        run += myv[i];
    }
}

// block per bucket: 128-wide scan of cnt -> rowptr, fused invc
__global__ void k_rowptr(const int* __restrict__ cnt, const int* __restrict__ boff,
                         int* __restrict__ rowptr, float* __restrict__ invc, int n, int NB) {
    __shared__ int ls[128];
    int b = blockIdx.x, t = threadIdx.x;
    int node = b * 128 + t;
    int c = (node < n) ? cnt[node] : 0;
    ls[t] = c;
    __syncthreads();
    for (int off = 1; off < 128; off <<= 1) {
        int u = (t >= off) ? ls[t - off] : 0;
        __syncthreads();
        ls[t] += u;
        __syncthreads();
    }
    int ex = ls[t] - c + boff[b];
    if (node < n) {
        rowptr[node] = ex;
        invc[node] = 1.0f / fmaxf((float)c, 1.0f);
    }
    if (b == NB - 1 && t == 127) rowptr[n] = boff[b] + ls[127];
}

// block per bucket: scatter src into contiguous output window
__global__ void k_scat2(const int* __restrict__ bcur, const unsigned* __restrict__ tmp,
                        const int* __restrict__ rowptr, int* __restrict__ srclist, int n) {
    __shared__ int cur[128];
    int b = blockIdx.x, t = threadIdx.x;
    if (t < 128) {
        int node = b * 128 + t;
        cur[t] = (node < n) ? rowptr[node] : 0;
    }
    __syncthreads();
    int cb = bcur[b];
    const unsigned* tb = tmp + (size_t)b * BCAP;
    for (int i = t; i < cb; i += 256) {
        unsigned v = tb[i];
        int pos = atomicAdd(&cur[v & 127], 1);
        srclist[pos] = (int)(v >> 7);
    }
}

__global__ void k_mark(const int* __restrict__ nidx, int* __restrict__ mark,
                       int* __restrict__ list, int* __restrict__ nmarked, int M) {
    int m = blockIdx.x * blockDim.x + threadIdx.x;
    if (m < M) {
        int n = nidx[m];
        if (atomicExch(&mark[n], 1) == 0) list[atomicAdd(nmarked, 1)] = n;
    }
}

// ---------------- conversions ----------------

__global__ void k_tobf16(const float* __restrict__ in, unsigned short* __restrict__ out, int n4) {
    int i = blockIdx.x * blockDim.x + threadIdx.x;
    int stride = gridDim.x * blockDim.x;
    for (; i < n4; i += stride) {
        float4 v = ((const float4*)in)[i];
        ushort4 u;
        u.x = f2b(v.x); u.y = f2b(v.y); u.z = f2b(v.z); u.w = f2b(v.w);
        ((ushort4*)out)[i] = u;
    }
}

// offsets: W1l 0, W1r 16384, W2l 32768, W2r 49152, fcW1 65536, fcW2 81920 (total 90112)
__global__ void k_wconv(const float* __restrict__ W1l, const float* __restrict__ W1r,
                        const float* __restrict__ W2l, const float* __restrict__ W2r,
                        const float* __restrict__ fcW1, const float* __restrict__ fcW2,
                        unsigned short* __restrict__ Wb) {
    int i = blockIdx.x * blockDim.x + threadIdx.x;
    if (i >= 90112) return;
    float v;
    if (i < 16384) v = W1l[i];
    else if (i < 32768) v = W1r[i - 16384];
    else if (i < 49152) v = W2l[i - 32768];
    else if (i < 65536) v = W2r[i - 49152];
    else if (i < 81920) v = fcW1[i - 65536];
    else v = fcW2[i - 81920];
    Wb[i] = f2b(v);
}

// ---------------- aggregation (bf16 feat): wave per dst node, fused mean ----------------
__global__ void k_aggr_b(const int* __restrict__ rowptr, const int* __restrict__ srclist,
                         const unsigned int* __restrict__ feat, const float* __restrict__ invc,
                         const int* __restrict__ list, const int* __restrict__ nlist,
                         unsigned int* __restrict__ outf, int n) {
    int lane = threadIdx.x & 63;
    int w = blockIdx.x * (blockDim.x >> 6) + (threadIdx.x >> 6);
    int node;
    if (list) {
        int nm = *nlist;
        if (w >= nm) return;
        node = list[w];
    } else {
        if (w >= n) return;
        node = w;
    }
    int beg = rowptr[node], end = rowptr[node + 1];
    float a0 = 0.f, a1 = 0.f;
    int i = beg;
    for (; i + 4 <= end; i += 4) {
        unsigned u0 = feat[(size_t)srclist[i] * 64 + lane];
        unsigned u1 = feat[(size_t)srclist[i + 1] * 64 + lane];
        unsigned u2 = feat[(size_t)srclist[i + 2] * 64 + lane];
        unsigned u3 = feat[(size_t)srclist[i + 3] * 64 + lane];
        a0 += __uint_as_float(u0 << 16) + __uint_as_float(u1 << 16) +
              __uint_as_float(u2 << 16) + __uint_as_float(u3 << 16);
        a1 += __uint_as_float(u0 & 0xffff0000u) + __uint_as_float(u1 & 0xffff0000u) +
              __uint_as_float(u2 & 0xffff0000u) + __uint_as_float(u3 & 0xffff0000u);
    }
    for (; i < end; i++) {
        unsigned u = feat[(size_t)srclist[i] * 64 + lane];
        a0 += __uint_as_float(u << 16);
        a1 += __uint_as_float(u & 0xffff0000u);
    }
    float ic = invc[node];
    a0 *= ic; a1 *= ic;
    outf[(size_t)node * 64 + lane] = ((unsigned)f2b(a1) << 16) | (unsigned)f2b(a0);
}

// ---------------- MFMA dense: out = A@Wl.T (+ X@Wr.T) + b ----------------
template <int NCT, int TWO, int RELU, int OUTBF>
__global__ void k_mdense(const unsigned short* __restrict__ A,
                         const unsigned short* __restrict__ X,
                         const int* __restrict__ gidx,
                         const unsigned short* __restrict__ Wl,
                         const float* __restrict__ bl,
                         const unsigned short* __restrict__ Wr,
                         void* __restrict__ outp, int nrows) {
    const int OC = NCT * 16;
    int lane = threadIdx.x & 63;
    int wave = threadIdx.x >> 6;
    int rowBase = (blockIdx.x * 4 + wave) * 32;
    if (rowBase >= nrows) return;
    int rl = lane & 15;
    int ks = lane >> 4;
    int r0 = rowBase + rl, r1 = r0 + 16;
    int n0 = gidx ? gidx[r0] : r0;
    int n1 = gidx ? gidx[r1] : r1;
    f32x4 acc0[NCT], acc1[NCT];
#pragma unroll
    for (int ct = 0; ct < NCT; ct++) {
        acc0[ct] = (f32x4)0.f;
        acc1[ct] = (f32x4)0.f;
    }
#pragma unroll
    for (int pass = 0; pass < (TWO ? 2 : 1); pass++) {
        const unsigned short* Ain = pass ? X : A;
        const unsigned short* W = pass ? Wr : Wl;
        const s16x8* a0p = (const s16x8*)(Ain + (size_t)n0 * 128);
        const s16x8* a1p = (const s16x8*)(Ain + (size_t)n1 * 128);
#pragma unroll
        for (int kc = 0; kc < 4; kc++) {
            s16x8 af0 = a0p[kc * 4 + ks];
            s16x8 af1 = a1p[kc * 4 + ks];
#pragma unroll
            for (int ct = 0; ct < NCT; ct++) {
                const s16x8* bp = (const s16x8*)(W + (size_t)(ct * 16 + rl) * 128);
                s16x8 bf = bp[kc * 4 + ks];
                acc0[ct] = __builtin_amdgcn_mfma_f32_16x16x32_bf16(af0, bf, acc0[ct], 0, 0, 0);
                acc1[ct] = __builtin_amdgcn_mfma_f32_16x16x32_bf16(af1, bf, acc1[ct], 0, 0, 0);
            }
        }
    }
#pragma unroll
    for (int ct = 0; ct < NCT; ct++) {
        int col = ct * 16 + rl;
        float bj = bl[col];
#pragma unroll
        for (int j = 0; j < 4; j++) {
            int or0 = rowBase + ks * 4 + j;
            int or1 = or0 + 16;
            float v0 = acc0[ct][j] + bj;
            float v1 = acc1[ct][j] + bj;
            if (RELU) { v0 = fmaxf(v0, 0.f); v1 = fmaxf(v1, 0.f); }
            if (OUTBF) {
                ((unsigned short*)outp)[(size_t)or0 * OC + col] = f2b(v0);
                ((unsigned short*)outp)[(size_t)or1 * OC + col] = f2b(v1);
            } else {
                ((float*)outp)[(size_t)or0 * OC + col] = v0;
                ((float*)outp)[(size_t)or1 * OC + col] = v1;
            }
        }
    }
}

// ---------------- batchnorm ----------------
template <int C>
__global__ void k_bnstats(const float* __restrict__ z, float* __restrict__ gsum,
                          float* __restrict__ gsq, int nrows, int rowsPerBlock) {
    int t = threadIdx.x;
    int c = t % C;
    int g = t / C;
    const int G = 256 / C;
    int r0 = blockIdx.x * rowsPerBlock;
    int r1 = min(r0 + rowsPerBlock, nrows);
    float s = 0.f, q = 0.f;
    for (int r = r0 + g; r < r1; r += G) {
        float v = z[(size_t)r * C + c];
        s += v;
        q += v * v;
    }
    __shared__ float ls[256], lq[256];
    ls[t] = s;
    lq[t] = q;
    __syncthreads();
    if (t < C) {
        for (int g2 = 1; g2 < G; g2++) {
            s += ls[g2 * C + c];
            q += lq[g2 * C + c];
        }
        atomicAdd(&gsum[c], s);
        atomicAdd(&gsq[c], q);
    }
}

__global__ void k_bnprep(const float* __restrict__ gsum, const float* __restrict__ gsq,
                         const float* __restrict__ gamma, const float* __restrict__ beta,
                         float* __restrict__ scale, float* __restrict__ shift, int C, float invM) {
    int c = blockIdx.x * blockDim.x + threadIdx.x;
    if (c < C) {
        float mean = gsum[c] * invM;
        float var = gsq[c] * invM - mean * mean;
        float is = rsqrtf(var + EPSV);
        float sc = gamma[c] * is;
        scale[c] = sc;
        shift[c] = beta[c] - mean * sc;
    }
}

template <int OUTBF>
__global__ void k_bn_act(const float* __restrict__ z, const float* __restrict__ scale,
                         const float* __restrict__ shift, void* __restrict__ outp,
                         int total, int colsMask, float slope) {
    int i = blockIdx.x * blockDim.x + threadIdx.x;
    if (i < total) {
        int c = i & colsMask;
        float y = z[i] * scale[c] + shift[c];
        y = (y >= 0.f) ? y : slope * y;
        if (OUTBF) ((unsigned short*)outp)[i] = f2b(y);
        else ((float*)outp)[i] = y;
    }
}

// ---------------- final fc3 ----------------
__global__ void k_fc3(const float* __restrict__ z2, const float* __restrict__ w,
                      const float* __restrict__ b, float* __restrict__ out, int nrows) {
    int lane = threadIdx.x & 63;
    int m = blockIdx.x * (blockDim.x >> 6) + (threadIdx.x >> 6);
    if (m >= nrows) return;
    float v = z2[(size_t)m * 64 + lane] * w[lane];
    for (int off = 32; off > 0; off >>= 1) v += __shfl_down(v, off);
    if (lane == 0) out[m] = v + b[0];
}

// ---------------- launch ----------------
extern "C" void kernel_launch(void* const* d_in, const int* in_sizes, int n_in,
                              void* d_out, int out_size, void* d_ws, size_t ws_size,
                              hipStream_t stream) {
    const float* x    = (const float*)d_in[0];
    const int*   ei   = (const int*)d_in[1];
    const int*   nidx = (const int*)d_in[2];
    const float* W1l  = (const float*)d_in[3];
    const float* b1   = (const float*)d_in[4];
    const float* W1r  = (const float*)d_in[5];
    const float* W2l  = (const float*)d_in[6];
    const float* b2   = (const float*)d_in[7];
    const float* W2r  = (const float*)d_in[8];
    const float* fcW1 = (const float*)d_in[9];
    const float* fcb1 = (const float*)d_in[10];
    const float* fcW2 = (const float*)d_in[11];
    const float* fcb2 = (const float*)d_in[12];
    const float* fcW3 = (const float*)d_in[13];
    const float* fcb3 = (const float*)d_in[14];
    const float* g1   = (const float*)d_in[15];
    const float* be1  = (const float*)d_in[16];
    const float* g2   = (const float*)d_in[17];
    const float* be2  = (const float*)d_in[18];

    const int N = in_sizes[0] / 128;
    const int E = in_sizes[1] / 2;
    const int M = in_sizes[2];
    const int* src = ei;
    const int* dst = ei + E;
    const int NB = (N + 127) / 128;  // 782 buckets

    char* ws = (char*)d_ws;
    size_t off = 0;
    unsigned short* xb  = (unsigned short*)(ws + off); off += (size_t)N * 128 * 2;
    unsigned short* sb  = (unsigned short*)(ws + off); off += (size_t)N * 128 * 2;
    unsigned short* h1b = (unsigned short*)(ws + off); off += (size_t)N * 128 * 2;
    unsigned short* z0b = (unsigned short*)(ws + off); off += (size_t)M * 128 * 2;
    float* z1           = (float*)(ws + off);          off += (size_t)M * 128 * 4;
    unsigned short* z1b = (unsigned short*)(ws + off); off += (size_t)M * 128 * 2;
    float* z2           = (float*)(ws + off);          off += (size_t)M * 64 * 4;
    unsigned short* Wb  = (unsigned short*)(ws + off); off += 90112 * 2;
    unsigned* tmp  = (unsigned*)(ws + off); off += (size_t)NB * BCAP * 4;
    int*   bcur    = (int*)(ws + off);   off += (size_t)NB * 4;
    int*   boff    = (int*)(ws + off);   off += (size_t)NB * 4;
    int*   cnt     = (int*)(ws + off);   off += (size_t)N * 4;
    float* invc    = (float*)(ws + off); off += (size_t)N * 4;
    int*   mark    = (int*)(ws + off);   off += (size_t)N * 4;
    int*   rowptr  = (int*)(ws + off);   off += (size_t)(N + 1) * 4;
    int*   srclist = (int*)(ws + off);   off += (size_t)E * 4;
    int*   list    = (int*)(ws + off);   off += (size_t)M * 4;
    int*   nmarked = (int*)(ws + off);   off += 64;
    float* gsum1   = (float*)(ws + off); off += 128 * 4;
    float* gsq1    = (float*)(ws + off); off += 128 * 4;
    float* scale1  = (float*)(ws + off); off += 128 * 4;
    float* shift1  = (float*)(ws + off); off += 128 * 4;
    float* gsum2   = (float*)(ws + off); off += 64 * 4;
    float* gsq2    = (float*)(ws + off); off += 64 * 4;
    float* scale2  = (float*)(ws + off); off += 64 * 4;
    float* shift2  = (float*)(ws + off); off += 64 * 4;
    float* out = (float*)d_out;

    hipMemsetAsync(bcur, 0, (size_t)NB * 4, stream);
    hipMemsetAsync(mark, 0, (size_t)N * 4, stream);
    hipMemsetAsync(nmarked, 0, 4, stream);
    hipMemsetAsync(gsum1, 0, (128 + 128 + 128 + 128 + 64 + 64 + 64 + 64) * 4, stream);

    // conversions (independent of CSR build)
    k_wconv<<<(90112 + 255) / 256, 256, 0, stream>>>(W1l, W1r, W2l, W2r, fcW1, fcW2, Wb);
    k_tobf16<<<2048, 256, 0, stream>>>(x, xb, N * 128 / 4);

    // bucketed CSR build
    k_bin<<<(E + 255) / 256, 256, 0, stream>>>(src, dst, bcur, tmp, E);
    k_bcount<<<NB, 256, 0, stream>>>(bcur, tmp, cnt, N);
    k_scanb2<<<1, 256, 0, stream>>>(bcur, boff, NB);
    k_rowptr<<<NB, 128, 0, stream>>>(cnt, boff, rowptr, invc, N, NB);
    k_scat2<<<NB, 256, 0, stream>>>(bcur, tmp, rowptr, srclist, N);
    k_mark<<<(M + 255) / 256, 256, 0, stream>>>(nidx, mark, list, nmarked, M);

    // layer 1
    k_aggr_b<<<(N + 3) / 4, 256, 0, stream>>>(rowptr, srclist, (const unsigned int*)xb, invc,
                                              nullptr, nullptr, (unsigned int*)sb, N);
    k_mdense<8, 1, 1, 1><<<(N / 32 + 3) / 4, 256, 0, stream>>>(
        sb, xb, nullptr, Wb + 0, b1, Wb + 16384, h1b, N);

    // layer 2 (only marked dst nodes)
    k_aggr_b<<<(M + 3) / 4, 256, 0, stream>>>(rowptr, srclist, (const unsigned int*)h1b, invc,
                                              list, nmarked, (unsigned int*)sb, N);
    k_mdense<8, 1, 0, 1><<<(M / 32 + 3) / 4, 256, 0, stream>>>(
        sb, h1b, nidx, Wb + 32768, b2, Wb + 49152, z0b, M);

    // MLP head
    k_mdense<8, 0, 0, 0><<<(M / 32 + 3) / 4, 256, 0, stream>>>(
        z0b, nullptr, nullptr, Wb + 65536, fcb1, nullptr, z1, M);
    k_bnstats<128><<<(M + 99) / 100, 256, 0, stream>>>(z1, gsum1, gsq1, M, 100);
    k_bnprep<<<1, 128, 0, stream>>>(gsum1, gsq1, g1, be1, scale1, shift1, 128, 1.0f / M);
    k_bn_act<1><<<((size_t)M * 128 + 255) / 256, 256, 0, stream>>>(
        z1, scale1, shift1, z1b, M * 128, 127, 0.1f);

    k_mdense<4, 0, 0, 0><<<(M / 32 + 3) / 4, 256, 0, stream>>>(
        z1b, nullptr, nullptr, Wb + 81920, fcb2, nullptr, z2, M);
    k_bnstats<64><<<(M + 99) / 100, 256, 0, stream>>>(z2, gsum2, gsq2, M, 100);
    k_bnprep<<<1, 64, 0, stream>>>(gsum2, gsq2, g2, be2, scale2, shift2, 64, 1.0f / M);
    k_bn_act<0><<<((size_t)M * 64 + 255) / 256, 256, 0, stream>>>(
        z2, scale2, shift2, z2, M * 64, 63, 0.05f);

    k_fc3<<<(M + 3) / 4, 256, 0, stream>>>(z2, fcW3, fcb3, out, M);
}

// Round 7
// 574.315 us; speedup vs baseline: 1.3257x; 1.3257x over previous
//
#include <hip/hip_runtime.h>
#include <hip/hip_bf16.h>

#define EPSV 1e-5f

typedef __attribute__((ext_vector_type(8))) short s16x8;
typedef __attribute__((ext_vector_type(4))) float f32x4;

static __device__ __forceinline__ unsigned short f2b(float f) {
    __hip_bfloat16 h = __float2bfloat16(f);
    return *reinterpret_cast<unsigned short*>(&h);
}

// ---------------- linked-list graph build ----------------
// head[node] -> most recent edge id; pk[e] = {next_edge, src_node}

__global__ void k_link(const int* __restrict__ src, const int* __restrict__ dst,
                       int* __restrict__ head, int2* __restrict__ pk, int E) {
    int e = blockIdx.x * blockDim.x + threadIdx.x;
    if (e < E) {
        int h = atomicExch(&head[dst[e]], e);
        pk[e] = make_int2(h, src[e]);
    }
}

__global__ void k_mark(const int* __restrict__ nidx, int* __restrict__ mark,
                       int* __restrict__ list, int* __restrict__ nmarked, int M) {
    int m = blockIdx.x * blockDim.x + threadIdx.x;
    if (m < M) {
        int n = nidx[m];
        if (atomicExch(&mark[n], 1) == 0) list[atomicAdd(nmarked, 1)] = n;
    }
}

// ---------------- conversions ----------------

__global__ void k_tobf16(const float* __restrict__ in, unsigned short* __restrict__ out, int n4) {
    int i = blockIdx.x * blockDim.x + threadIdx.x;
    int stride = gridDim.x * blockDim.x;
    for (; i < n4; i += stride) {
        float4 v = ((const float4*)in)[i];
        ushort4 u;
        u.x = f2b(v.x); u.y = f2b(v.y); u.z = f2b(v.z); u.w = f2b(v.w);
        ((ushort4*)out)[i] = u;
    }
}

// offsets: W1l 0, W1r 16384, W2l 32768, W2r 49152, fcW1 65536, fcW2 81920 (total 90112)
__global__ void k_wconv(const float* __restrict__ W1l, const float* __restrict__ W1r,
                        const float* __restrict__ W2l, const float* __restrict__ W2r,
                        const float* __restrict__ fcW1, const float* __restrict__ fcW2,
                        unsigned short* __restrict__ Wb) {
    int i = blockIdx.x * blockDim.x + threadIdx.x;
    if (i >= 90112) return;
    float v;
    if (i < 16384) v = W1l[i];
    else if (i < 32768) v = W1r[i - 16384];
    else if (i < 49152) v = W2l[i - 32768];
    else if (i < 65536) v = W2r[i - 49152];
    else if (i < 81920) v = fcW1[i - 65536];
    else v = fcW2[i - 81920];
    Wb[i] = f2b(v);
}

// ---------------- aggregation: wave walks 4 chains, fused mean ----------------
__global__ void k_aggr_chase(const int* __restrict__ head, const int2* __restrict__ pk,
                             const unsigned* __restrict__ feat,
                             const int* __restrict__ list, const int* __restrict__ nlist,
                             unsigned* __restrict__ outf, int n) {
    int lane = threadIdx.x & 63;
    int w = blockIdx.x * (blockDim.x >> 6) + (threadIdx.x >> 6);
    int limit = list ? *nlist : n;
    int node[4], e[4], cnt[4];
    float a0[4], a1[4];
#pragma unroll
    for (int c = 0; c < 4; c++) {
        int idx = w * 4 + c;
        node[c] = (idx < limit) ? (list ? list[idx] : idx) : -1;
        e[c] = (node[c] >= 0) ? head[node[c]] : -1;
        a0[c] = 0.f; a1[c] = 0.f; cnt[c] = 0;
    }
    while (e[0] >= 0 || e[1] >= 0 || e[2] >= 0 || e[3] >= 0) {
#pragma unroll
        for (int c = 0; c < 4; c++) {
            if (e[c] >= 0) {
                int2 p = pk[e[c]];
                unsigned u = feat[(size_t)p.y * 64 + lane];
                a0[c] += __uint_as_float(u << 16);
                a1[c] += __uint_as_float(u & 0xffff0000u);
                cnt[c]++;
                e[c] = p.x;
            }
        }
    }
#pragma unroll
    for (int c = 0; c < 4; c++) {
        if (node[c] >= 0) {
            float ic = 1.0f / fmaxf((float)cnt[c], 1.0f);
            float v0 = a0[c] * ic, v1 = a1[c] * ic;
            outf[(size_t)node[c] * 64 + lane] =
                ((unsigned)f2b(v1) << 16) | (unsigned)f2b(v0);
        }
    }
}

// ---------------- MFMA dense: out = A@Wl.T (+ X@Wr.T) + b ----------------
template <int NCT, int TWO, int RELU, int OUTBF>
__global__ void k_mdense(const unsigned short* __restrict__ A,
                         const unsigned short* __restrict__ X,
                         const int* __restrict__ gidx,
                         const unsigned short* __restrict__ Wl,
                         const float* __restrict__ bl,
                         const unsigned short* __restrict__ Wr,
                         void* __restrict__ outp, int nrows) {
    const int OC = NCT * 16;
    int lane = threadIdx.x & 63;
    int wave = threadIdx.x >> 6;
    int rowBase = (blockIdx.x * 4 + wave) * 32;
    if (rowBase >= nrows) return;
    int rl = lane & 15;
    int ks = lane >> 4;
    int r0 = rowBase + rl, r1 = r0 + 16;
    int n0 = gidx ? gidx[r0] : r0;
    int n1 = gidx ? gidx[r1] : r1;
    f32x4 acc0[NCT], acc1[NCT];
#pragma unroll
    for (int ct = 0; ct < NCT; ct++) {
        acc0[ct] = (f32x4)0.f;
        acc1[ct] = (f32x4)0.f;
    }
#pragma unroll
    for (int pass = 0; pass < (TWO ? 2 : 1); pass++) {
        const unsigned short* Ain = pass ? X : A;
        const unsigned short* W = pass ? Wr : Wl;
        const s16x8* a0p = (const s16x8*)(Ain + (size_t)n0 * 128);
        const s16x8* a1p = (const s16x8*)(Ain + (size_t)n1 * 128);
#pragma unroll
        for (int kc = 0; kc < 4; kc++) {
            s16x8 af0 = a0p[kc * 4 + ks];
            s16x8 af1 = a1p[kc * 4 + ks];
#pragma unroll
            for (int ct = 0; ct < NCT; ct++) {
                const s16x8* bp = (const s16x8*)(W + (size_t)(ct * 16 + rl) * 128);
                s16x8 bf = bp[kc * 4 + ks];
                acc0[ct] = __builtin_amdgcn_mfma_f32_16x16x32_bf16(af0, bf, acc0[ct], 0, 0, 0);
                acc1[ct] = __builtin_amdgcn_mfma_f32_16x16x32_bf16(af1, bf, acc1[ct], 0, 0, 0);
            }
        }
    }
#pragma unroll
    for (int ct = 0; ct < NCT; ct++) {
        int col = ct * 16 + rl;
        float bj = bl[col];
#pragma unroll
        for (int j = 0; j < 4; j++) {
            int or0 = rowBase + ks * 4 + j;
            int or1 = or0 + 16;
            float v0 = acc0[ct][j] + bj;
            float v1 = acc1[ct][j] + bj;
            if (RELU) { v0 = fmaxf(v0, 0.f); v1 = fmaxf(v1, 0.f); }
            if (OUTBF) {
                ((unsigned short*)outp)[(size_t)or0 * OC + col] = f2b(v0);
                ((unsigned short*)outp)[(size_t)or1 * OC + col] = f2b(v1);
            } else {
                ((float*)outp)[(size_t)or0 * OC + col] = v0;
                ((float*)outp)[(size_t)or1 * OC + col] = v1;
            }
        }
    }
}

// ---------------- batchnorm ----------------
template <int C>
__global__ void k_bnstats(const float* __restrict__ z, float* __restrict__ gsum,
                          float* __restrict__ gsq, int nrows, int rowsPerBlock) {
    int t = threadIdx.x;
    int c = t % C;
    int g = t / C;
    const int G = 256 / C;
    int r0 = blockIdx.x * rowsPerBlock;
    int r1 = min(r0 + rowsPerBlock, nrows);
    float s = 0.f, q = 0.f;
    for (int r = r0 + g; r < r1; r += G) {
        float v = z[(size_t)r * C + c];
        s += v;
        q += v * v;
    }
    __shared__ float ls[256], lq[256];
    ls[t] = s;
    lq[t] = q;
    __syncthreads();
    if (t < C) {
        for (int g2 = 1; g2 < G; g2++) {
            s += ls[g2 * C + c];
            q += lq[g2 * C + c];
        }
        atomicAdd(&gsum[c], s);
        atomicAdd(&gsq[c], q);
    }
}

__global__ void k_bnprep(const float* __restrict__ gsum, const float* __restrict__ gsq,
                         const float* __restrict__ gamma, const float* __restrict__ beta,
                         float* __restrict__ scale, float* __restrict__ shift, int C, float invM) {
    int c = blockIdx.x * blockDim.x + threadIdx.x;
    if (c < C) {
        float mean = gsum[c] * invM;
        float var = gsq[c] * invM - mean * mean;
        float is = rsqrtf(var + EPSV);
        float sc = gamma[c] * is;
        scale[c] = sc;
        shift[c] = beta[c] - mean * sc;
    }
}

template <int OUTBF>
__global__ void k_bn_act(const float* __restrict__ z, const float* __restrict__ scale,
                         const float* __restrict__ shift, void* __restrict__ outp,
                         int total, int colsMask, float slope) {
    int i = blockIdx.x * blockDim.x + threadIdx.x;
    if (i < total) {
        int c = i & colsMask;
        float y = z[i] * scale[c] + shift[c];
        y = (y >= 0.f) ? y : slope * y;
        if (OUTBF) ((unsigned short*)outp)[i] = f2b(y);
        else ((float*)outp)[i] = y;
    }
}

// ---------------- final fc3 ----------------
__global__ void k_fc3(const float* __restrict__ z2, const float* __restrict__ w,
                      const float* __restrict__ b, float* __restrict__ out, int nrows) {
    int lane = threadIdx.x & 63;
    int m = blockIdx.x * (blockDim.x >> 6) + (threadIdx.x >> 6);
    if (m >= nrows) return;
    float v = z2[(size_t)m * 64 + lane] * w[lane];
    for (int off = 32; off > 0; off >>= 1) v += __shfl_down(v, off);
    if (lane == 0) out[m] = v + b[0];
}

// ---------------- launch ----------------
extern "C" void kernel_launch(void* const* d_in, const int* in_sizes, int n_in,
                              void* d_out, int out_size, void* d_ws, size_t ws_size,
                              hipStream_t stream) {
    const float* x    = (const float*)d_in[0];
    const int*   ei   = (const int*)d_in[1];
    const int*   nidx = (const int*)d_in[2];
    const float* W1l  = (const float*)d_in[3];
    const float* b1   = (const float*)d_in[4];
    const float* W1r  = (const float*)d_in[5];
    const float* W2l  = (const float*)d_in[6];
    const float* b2   = (const float*)d_in[7];
    const float* W2r  = (const float*)d_in[8];
    const float* fcW1 = (const float*)d_in[9];
    const float* fcb1 = (const float*)d_in[10];
    const float* fcW2 = (const float*)d_in[11];
    const float* fcb2 = (const float*)d_in[12];
    const float* fcW3 = (const float*)d_in[13];
    const float* fcb3 = (const float*)d_in[14];
    const float* g1   = (const float*)d_in[15];
    const float* be1  = (const float*)d_in[16];
    const float* g2   = (const float*)d_in[17];
    const float* be2  = (const float*)d_in[18];

    const int N = in_sizes[0] / 128;
    const int E = in_sizes[1] / 2;
    const int M = in_sizes[2];
    const int* src = ei;
    const int* dst = ei + E;

    char* ws = (char*)d_ws;
    size_t off = 0;
    unsigned short* xb  = (unsigned short*)(ws + off); off += (size_t)N * 128 * 2;
    unsigned short* sb  = (unsigned short*)(ws + off); off += (size_t)N * 128 * 2;
    unsigned short* h1b = (unsigned short*)(ws + off); off += (size_t)N * 128 * 2;
    unsigned short* z0b = (unsigned short*)(ws + off); off += (size_t)M * 128 * 2;
    float* z1           = (float*)(ws + off);          off += (size_t)M * 128 * 4;
    unsigned short* z1b = (unsigned short*)(ws + off); off += (size_t)M * 128 * 2;
    float* z2           = (float*)(ws + off);          off += (size_t)M * 64 * 4;
    unsigned short* Wb  = (unsigned short*)(ws + off); off += 90112 * 2;
    int2* pk       = (int2*)(ws + off);  off += (size_t)E * 8;
    int*  head     = (int*)(ws + off);   off += (size_t)N * 4;
    int*  mark     = (int*)(ws + off);   off += (size_t)N * 4;
    int*  list     = (int*)(ws + off);   off += (size_t)M * 4;
    int*  nmarked  = (int*)(ws + off);   off += 64;
    float* gsum1   = (float*)(ws + off); off += 128 * 4;
    float* gsq1    = (float*)(ws + off); off += 128 * 4;
    float* scale1  = (float*)(ws + off); off += 128 * 4;
    float* shift1  = (float*)(ws + off); off += 128 * 4;
    float* gsum2   = (float*)(ws + off); off += 64 * 4;
    float* gsq2    = (float*)(ws + off); off += 64 * 4;
    float* scale2  = (float*)(ws + off); off += 64 * 4;
    float* shift2  = (float*)(ws + off); off += 64 * 4;
    float* out = (float*)d_out;

    hipMemsetAsync(head, 0xFF, (size_t)N * 4, stream);   // head = -1
    hipMemsetAsync(mark, 0, (size_t)N * 4, stream);
    hipMemsetAsync(nmarked, 0, 4, stream);
    hipMemsetAsync(gsum1, 0, (128 + 128 + 128 + 128 + 64 + 64 + 64 + 64) * 4, stream);

    // conversions (independent of graph build)
    k_wconv<<<(90112 + 255) / 256, 256, 0, stream>>>(W1l, W1r, W2l, W2r, fcW1, fcW2, Wb);
    k_tobf16<<<2048, 256, 0, stream>>>(x, xb, N * 128 / 4);

    // graph build: per-node linked lists
    k_link<<<(E + 255) / 256, 256, 0, stream>>>(src, dst, head, pk, E);
    k_mark<<<(M + 255) / 256, 256, 0, stream>>>(nidx, mark, list, nmarked, M);

    // layer 1: aggregate all nodes
    {
        int waves = (N + 3) / 4;
        k_aggr_chase<<<(waves + 3) / 4, 256, 0, stream>>>(
            head, pk, (const unsigned*)xb, nullptr, nullptr, (unsigned*)sb, N);
    }
    k_mdense<8, 1, 1, 1><<<(N / 32 + 3) / 4, 256, 0, stream>>>(
        sb, xb, nullptr, Wb + 0, b1, Wb + 16384, h1b, N);

    // layer 2: aggregate only marked dst nodes
    {
        int waves = (M + 3) / 4;
        k_aggr_chase<<<(waves + 3) / 4, 256, 0, stream>>>(
            head, pk, (const unsigned*)h1b, list, nmarked, (unsigned*)sb, N);
    }
    k_mdense<8, 1, 0, 1><<<(M / 32 + 3) / 4, 256, 0, stream>>>(
        sb, h1b, nidx, Wb + 32768, b2, Wb + 49152, z0b, M);

    // MLP head
    k_mdense<8, 0, 0, 0><<<(M / 32 + 3) / 4, 256, 0, stream>>>(
        z0b, nullptr, nullptr, Wb + 65536, fcb1, nullptr, z1, M);
    k_bnstats<128><<<(M + 99) / 100, 256, 0, stream>>>(z1, gsum1, gsq1, M, 100);
    k_bnprep<<<1, 128, 0, stream>>>(gsum1, gsq1, g1, be1, scale1, shift1, 128, 1.0f / M);
    k_bn_act<1><<<((size_t)M * 128 + 255) / 256, 256, 0, stream>>>(
        z1, scale1, shift1, z1b, M * 128, 127, 0.1f);

    k_mdense<4, 0, 0, 0><<<(M / 32 + 3) / 4, 256, 0, stream>>>(
        z1b, nullptr, nullptr, Wb + 81920, fcb2, nullptr, z2, M);
    k_bnstats<64><<<(M + 99) / 100, 256, 0, stream>>>(z2, gsum2, gsq2, M, 100);
    k_bnprep<<<1, 64, 0, stream>>>(gsum2, gsq2, g2, be2, scale2, shift2, 64, 1.0f / M);
    k_bn_act<0><<<((size_t)M * 64 + 255) / 256, 256, 0, stream>>>(
        z2, scale2, shift2, z2, M * 64, 63, 0.05f);

    k_fc3<<<(M + 3) / 4, 256, 0, stream>>>(z2, fcW3, fcb3, out, M);
}

// Round 8
// 458.504 us; speedup vs baseline: 1.6606x; 1.2526x over previous
//
#include <hip/hip_runtime.h>
#include <hip/hip_bf16.h>

#define EPSV 1e-5f

typedef __attribute__((ext_vector_type(8))) short s16x8;
typedef __attribute__((ext_vector_type(4))) float f32x4;

static __device__ __forceinline__ unsigned short f2b(float f) {
    __hip_bfloat16 h = __float2bfloat16(f);
    return *reinterpret_cast<unsigned short*>(&h);
}

// ---------------- linked-list graph build ----------------
// head[node] -> most recent edge id; pk[e] = {next_edge, src_node}

__global__ void k_link(const int* __restrict__ src, const int* __restrict__ dst,
                       int* __restrict__ head, int2* __restrict__ pk, int E) {
    int e = blockIdx.x * blockDim.x + threadIdx.x;
    if (e < E) {
        int h = atomicExch(&head[dst[e]], e);
        pk[e] = make_int2(h, src[e]);
    }
}

__global__ void k_mark(const int* __restrict__ nidx, int* __restrict__ mark,
                       int* __restrict__ list, int* __restrict__ nmarked, int M) {
    int m = blockIdx.x * blockDim.x + threadIdx.x;
    if (m < M) {
        int n = nidx[m];
        if (atomicExch(&mark[n], 1) == 0) list[atomicAdd(nmarked, 1)] = n;
    }
}

// ---------------- conversions ----------------

__global__ void k_tobf16(const float* __restrict__ in, unsigned short* __restrict__ out, int n4) {
    int i = blockIdx.x * blockDim.x + threadIdx.x;
    int stride = gridDim.x * blockDim.x;
    for (; i < n4; i += stride) {
        float4 v = ((const float4*)in)[i];
        ushort4 u;
        u.x = f2b(v.x); u.y = f2b(v.y); u.z = f2b(v.z); u.w = f2b(v.w);
        ((ushort4*)out)[i] = u;
    }
}

// offsets: W1l 0, W1r 16384, W2l 32768, W2r 49152, fcW1 65536, fcW2 81920 (total 90112)
__global__ void k_wconv(const float* __restrict__ W1l, const float* __restrict__ W1r,
                        const float* __restrict__ W2l, const float* __restrict__ W2r,
                        const float* __restrict__ fcW1, const float* __restrict__ fcW2,
                        unsigned short* __restrict__ Wb) {
    int i = blockIdx.x * blockDim.x + threadIdx.x;
    if (i >= 90112) return;
    float v;
    if (i < 16384) v = W1l[i];
    else if (i < 32768) v = W1r[i - 16384];
    else if (i < 49152) v = W2l[i - 32768];
    else if (i < 65536) v = W2r[i - 49152];
    else if (i < 81920) v = fcW1[i - 65536];
    else v = fcW2[i - 81920];
    Wb[i] = f2b(v);
}

// ---------------- aggregation: branchless software-pipelined 4-chain walk ----------------
__global__ void k_aggr_pl(const int* __restrict__ head, const int2* __restrict__ pk,
                          const unsigned* __restrict__ feat,
                          const int* __restrict__ list, const int* __restrict__ nlist,
                          unsigned* __restrict__ outf, int n) {
    int lane = threadIdx.x & 63;
    int w = blockIdx.x * (blockDim.x >> 6) + (threadIdx.x >> 6);
    int limit = list ? *nlist : n;
    int node[4], e[4], cnt[4];
    float a0[4], a1[4];
    int2 p[4];
#pragma unroll
    for (int c = 0; c < 4; c++) {
        int idx = w * 4 + c;
        node[c] = (idx < limit) ? (list ? list[idx] : idx) : -1;
        a0[c] = 0.f; a1[c] = 0.f; cnt[c] = 0;
    }
#pragma unroll
    for (int c = 0; c < 4; c++)
        e[c] = (node[c] >= 0) ? head[node[c]] : -1;
    // prologue: pk for current edges (masked to 0 when done)
#pragma unroll
    for (int c = 0; c < 4; c++)
        p[c] = pk[e[c] >= 0 ? e[c] : 0];

    while (max(max(e[0], e[1]), max(e[2], e[3])) >= 0) {
        // stage 1: issue all feat loads (independent, one waitcnt group)
        unsigned u[4];
#pragma unroll
        for (int c = 0; c < 4; c++) {
            int srcn = e[c] >= 0 ? p[c].y : 0;
            u[c] = feat[(size_t)srcn * 64 + lane];
        }
        // stage 2: issue next-step pk loads (hide pk latency under feat use)
        int2 pn[4];
#pragma unroll
        for (int c = 0; c < 4; c++) {
            int en = (e[c] >= 0 && p[c].x >= 0) ? p[c].x : 0;
            pn[c] = pk[en];
        }
        // stage 3: masked accumulate + advance
#pragma unroll
        for (int c = 0; c < 4; c++) {
            bool act = e[c] >= 0;
            float m = act ? 1.0f : 0.0f;
            a0[c] += m * __uint_as_float(u[c] << 16);
            a1[c] += m * __uint_as_float(u[c] & 0xffff0000u);
            cnt[c] += act ? 1 : 0;
            e[c] = act ? p[c].x : -1;
            p[c] = pn[c];
        }
    }
#pragma unroll
    for (int c = 0; c < 4; c++) {
        if (node[c] >= 0) {
            float ic = 1.0f / fmaxf((float)cnt[c], 1.0f);
            float v0 = a0[c] * ic, v1 = a1[c] * ic;
            outf[(size_t)node[c] * 64 + lane] =
                ((unsigned)f2b(v1) << 16) | (unsigned)f2b(v0);
        }
    }
}

// ---------------- MFMA dense: out = A@Wl.T (+ X@Wr.T) + b ----------------
template <int NCT, int TWO, int RELU, int OUTBF>
__global__ void k_mdense(const unsigned short* __restrict__ A,
                         const unsigned short* __restrict__ X,
                         const int* __restrict__ gidx,
                         const unsigned short* __restrict__ Wl,
                         const float* __restrict__ bl,
                         const unsigned short* __restrict__ Wr,
                         void* __restrict__ outp, int nrows) {
    const int OC = NCT * 16;
    int lane = threadIdx.x & 63;
    int wave = threadIdx.x >> 6;
    int rowBase = (blockIdx.x * 4 + wave) * 32;
    if (rowBase >= nrows) return;
    int rl = lane & 15;
    int ks = lane >> 4;
    int r0 = rowBase + rl, r1 = r0 + 16;
    int n0 = gidx ? gidx[r0] : r0;
    int n1 = gidx ? gidx[r1] : r1;
    f32x4 acc0[NCT], acc1[NCT];
#pragma unroll
    for (int ct = 0; ct < NCT; ct++) {
        acc0[ct] = (f32x4)0.f;
        acc1[ct] = (f32x4)0.f;
    }
#pragma unroll
    for (int pass = 0; pass < (TWO ? 2 : 1); pass++) {
        const unsigned short* Ain = pass ? X : A;
        const unsigned short* W = pass ? Wr : Wl;
        const s16x8* a0p = (const s16x8*)(Ain + (size_t)n0 * 128);
        const s16x8* a1p = (const s16x8*)(Ain + (size_t)n1 * 128);
#pragma unroll
        for (int kc = 0; kc < 4; kc++) {
            s16x8 af0 = a0p[kc * 4 + ks];
            s16x8 af1 = a1p[kc * 4 + ks];
#pragma unroll
            for (int ct = 0; ct < NCT; ct++) {
                const s16x8* bp = (const s16x8*)(W + (size_t)(ct * 16 + rl) * 128);
                s16x8 bf = bp[kc * 4 + ks];
                acc0[ct] = __builtin_amdgcn_mfma_f32_16x16x32_bf16(af0, bf, acc0[ct], 0, 0, 0);
                acc1[ct] = __builtin_amdgcn_mfma_f32_16x16x32_bf16(af1, bf, acc1[ct], 0, 0, 0);
            }
        }
    }
#pragma unroll
    for (int ct = 0; ct < NCT; ct++) {
        int col = ct * 16 + rl;
        float bj = bl[col];
#pragma unroll
        for (int j = 0; j < 4; j++) {
            int or0 = rowBase + ks * 4 + j;
            int or1 = or0 + 16;
            float v0 = acc0[ct][j] + bj;
            float v1 = acc1[ct][j] + bj;
            if (RELU) { v0 = fmaxf(v0, 0.f); v1 = fmaxf(v1, 0.f); }
            if (OUTBF) {
                ((unsigned short*)outp)[(size_t)or0 * OC + col] = f2b(v0);
                ((unsigned short*)outp)[(size_t)or1 * OC + col] = f2b(v1);
            } else {
                ((float*)outp)[(size_t)or0 * OC + col] = v0;
                ((float*)outp)[(size_t)or1 * OC + col] = v1;
            }
        }
    }
}

// ---------------- batchnorm ----------------
template <int C>
__global__ void k_bnstats(const float* __restrict__ z, float* __restrict__ gsum,
                          float* __restrict__ gsq, int nrows, int rowsPerBlock) {
    int t = threadIdx.x;
    int c = t % C;
    int g = t / C;
    const int G = 256 / C;
    int r0 = blockIdx.x * rowsPerBlock;
    int r1 = min(r0 + rowsPerBlock, nrows);
    float s = 0.f, q = 0.f;
    for (int r = r0 + g; r < r1; r += G) {
        float v = z[(size_t)r * C + c];
        s += v;
        q += v * v;
    }
    __shared__ float ls[256], lq[256];
    ls[t] = s;
    lq[t] = q;
    __syncthreads();
    if (t < C) {
        for (int g2 = 1; g2 < G; g2++) {
            s += ls[g2 * C + c];
            q += lq[g2 * C + c];
        }
        atomicAdd(&gsum[c], s);
        atomicAdd(&gsq[c], q);
    }
}

__global__ void k_bnprep(const float* __restrict__ gsum, const float* __restrict__ gsq,
                         const float* __restrict__ gamma, const float* __restrict__ beta,
                         float* __restrict__ scale, float* __restrict__ shift, int C, float invM) {
    int c = blockIdx.x * blockDim.x + threadIdx.x;
    if (c < C) {
        float mean = gsum[c] * invM;
        float var = gsq[c] * invM - mean * mean;
        float is = rsqrtf(var + EPSV);
        float sc = gamma[c] * is;
        scale[c] = sc;
        shift[c] = beta[c] - mean * sc;
    }
}

template <int OUTBF>
__global__ void k_bn_act(const float* __restrict__ z, const float* __restrict__ scale,
                         const float* __restrict__ shift, void* __restrict__ outp,
                         int total, int colsMask, float slope) {
    int i = blockIdx.x * blockDim.x + threadIdx.x;
    if (i < total) {
        int c = i & colsMask;
        float y = z[i] * scale[c] + shift[c];
        y = (y >= 0.f) ? y : slope * y;
        if (OUTBF) ((unsigned short*)outp)[i] = f2b(y);
        else ((float*)outp)[i] = y;
    }
}

// ---------------- final fc3 ----------------
__global__ void k_fc3(const float* __restrict__ z2, const float* __restrict__ w,
                      const float* __restrict__ b, float* __restrict__ out, int nrows) {
    int lane = threadIdx.x & 63;
    int m = blockIdx.x * (blockDim.x >> 6) + (threadIdx.x >> 6);
    if (m >= nrows) return;
    float v = z2[(size_t)m * 64 + lane] * w[lane];
    for (int off = 32; off > 0; off >>= 1) v += __shfl_down(v, off);
    if (lane == 0) out[m] = v + b[0];
}

// ---------------- launch ----------------
extern "C" void kernel_launch(void* const* d_in, const int* in_sizes, int n_in,
                              void* d_out, int out_size, void* d_ws, size_t ws_size,
                              hipStream_t stream) {
    const float* x    = (const float*)d_in[0];
    const int*   ei   = (const int*)d_in[1];
    const int*   nidx = (const int*)d_in[2];
    const float* W1l  = (const float*)d_in[3];
    const float* b1   = (const float*)d_in[4];
    const float* W1r  = (const float*)d_in[5];
    const float* W2l  = (const float*)d_in[6];
    const float* b2   = (const float*)d_in[7];
    const float* W2r  = (const float*)d_in[8];
    const float* fcW1 = (const float*)d_in[9];
    const float* fcb1 = (const float*)d_in[10];
    const float* fcW2 = (const float*)d_in[11];
    const float* fcb2 = (const float*)d_in[12];
    const float* fcW3 = (const float*)d_in[13];
    const float* fcb3 = (const float*)d_in[14];
    const float* g1   = (const float*)d_in[15];
    const float* be1  = (const float*)d_in[16];
    const float* g2   = (const float*)d_in[17];
    const float* be2  = (const float*)d_in[18];

    const int N = in_sizes[0] / 128;
    const int E = in_sizes[1] / 2;
    const int M = in_sizes[2];
    const int* src = ei;
    const int* dst = ei + E;

    char* ws = (char*)d_ws;
    size_t off = 0;
    unsigned short* xb  = (unsigned short*)(ws + off); off += (size_t)N * 128 * 2;
    unsigned short* sb  = (unsigned short*)(ws + off); off += (size_t)N * 128 * 2;
    unsigned short* h1b = (unsigned short*)(ws + off); off += (size_t)N * 128 * 2;
    unsigned short* z0b = (unsigned short*)(ws + off); off += (size_t)M * 128 * 2;
    float* z1           = (float*)(ws + off);          off += (size_t)M * 128 * 4;
    unsigned short* z1b = (unsigned short*)(ws + off); off += (size_t)M * 128 * 2;
    float* z2           = (float*)(ws + off);          off += (size_t)M * 64 * 4;
    unsigned short* Wb  = (unsigned short*)(ws + off); off += 90112 * 2;
    int2* pk       = (int2*)(ws + off);  off += (size_t)E * 8;
    int*  head     = (int*)(ws + off);   off += (size_t)N * 4;
    int*  mark     = (int*)(ws + off);   off += (size_t)N * 4;
    int*  list     = (int*)(ws + off);   off += (size_t)M * 4;
    int*  nmarked  = (int*)(ws + off);   off += 64;
    float* gsum1   = (float*)(ws + off); off += 128 * 4;
    float* gsq1    = (float*)(ws + off); off += 128 * 4;
    float* scale1  = (float*)(ws + off); off += 128 * 4;
    float* shift1  = (float*)(ws + off); off += 128 * 4;
    float* gsum2   = (float*)(ws + off); off += 64 * 4;
    float* gsq2    = (float*)(ws + off); off += 64 * 4;
    float* scale2  = (float*)(ws + off); off += 64 * 4;
    float* shift2  = (float*)(ws + off); off += 64 * 4;
    float* out = (float*)d_out;

    hipMemsetAsync(head, 0xFF, (size_t)N * 4, stream);   // head = -1
    hipMemsetAsync(mark, 0, (size_t)N * 4, stream);
    hipMemsetAsync(nmarked, 0, 4, stream);
    hipMemsetAsync(gsum1, 0, (128 + 128 + 128 + 128 + 64 + 64 + 64 + 64) * 4, stream);

    // conversions (independent of graph build)
    k_wconv<<<(90112 + 255) / 256, 256, 0, stream>>>(W1l, W1r, W2l, W2r, fcW1, fcW2, Wb);
    k_tobf16<<<2048, 256, 0, stream>>>(x, xb, N * 128 / 4);

    // graph build: per-node linked lists
    k_link<<<(E + 255) / 256, 256, 0, stream>>>(src, dst, head, pk, E);
    k_mark<<<(M + 255) / 256, 256, 0, stream>>>(nidx, mark, list, nmarked, M);

    // layer 1: aggregate all nodes
    {
        int waves = (N + 3) / 4;
        k_aggr_pl<<<(waves + 3) / 4, 256, 0, stream>>>(
            head, pk, (const unsigned*)xb, nullptr, nullptr, (unsigned*)sb, N);
    }
    k_mdense<8, 1, 1, 1><<<(N / 32 + 3) / 4, 256, 0, stream>>>(
        sb, xb, nullptr, Wb + 0, b1, Wb + 16384, h1b, N);

    // layer 2: aggregate only marked dst nodes
    {
        int waves = (M + 3) / 4;
        k_aggr_pl<<<(waves + 3) / 4, 256, 0, stream>>>(
            head, pk, (const unsigned*)h1b, list, nmarked, (unsigned*)sb, N);
    }
    k_mdense<8, 1, 0, 1><<<(M / 32 + 3) / 4, 256, 0, stream>>>(
        sb, h1b, nidx, Wb + 32768, b2, Wb + 49152, z0b, M);

    // MLP head
    k_mdense<8, 0, 0, 0><<<(M / 32 + 3) / 4, 256, 0, stream>>>(
        z0b, nullptr, nullptr, Wb + 65536, fcb1, nullptr, z1, M);
    k_bnstats<128><<<(M + 99) / 100, 256, 0, stream>>>(z1, gsum1, gsq1, M, 100);
    k_bnprep<<<1, 128, 0, stream>>>(gsum1, gsq1, g1, be1, scale1, shift1, 128, 1.0f / M);
    k_bn_act<1><<<((size_t)M * 128 + 255) / 256, 256, 0, stream>>>(
        z1, scale1, shift1, z1b, M * 128, 127, 0.1f);

    k_mdense<4, 0, 0, 0><<<(M / 32 + 3) / 4, 256, 0, stream>>>(
        z1b, nullptr, nullptr, Wb + 81920, fcb2, nullptr, z2, M);
    k_bnstats<64><<<(M + 99) / 100, 256, 0, stream>>>(z2, gsum2, gsq2, M, 100);
    k_bnprep<<<1, 64, 0, stream>>>(gsum2, gsq2, g2, be2, scale2, shift2, 64, 1.0f / M);
    k_bn_act<0><<<((size_t)M * 64 + 255) / 256, 256, 0, stream>>>(
        z2, scale2, shift2, z2, M * 64, 63, 0.05f);

    k_fc3<<<(M + 3) / 4, 256, 0, stream>>>(z2, fcW3, fcb3, out, M);
}

// Round 9
// 447.648 us; speedup vs baseline: 1.7009x; 1.0243x over previous
//
#include <hip/hip_runtime.h>
#include <hip/hip_bf16.h>

#define EPSV 1e-5f

typedef __attribute__((ext_vector_type(8))) short s16x8;
typedef __attribute__((ext_vector_type(4))) float f32x4;

static __device__ __forceinline__ unsigned short f2b(float f) {
    __hip_bfloat16 h = __float2bfloat16(f);
    return *reinterpret_cast<unsigned short*>(&h);
}

// ---------------- linked-list graph build ----------------
// head[node] -> most recent edge id; pk[e] = {next_edge, src_node}

__global__ void k_link(const int* __restrict__ src, const int* __restrict__ dst,
                       int* __restrict__ head, int2* __restrict__ pk, int E) {
    int e = blockIdx.x * blockDim.x + threadIdx.x;
    if (e < E) {
        int h = atomicExch(&head[dst[e]], e);
        pk[e] = make_int2(h, src[e]);
    }
}

__global__ void k_mark(const int* __restrict__ nidx, int* __restrict__ mark,
                       int* __restrict__ list, int* __restrict__ nmarked, int M) {
    int m = blockIdx.x * blockDim.x + threadIdx.x;
    if (m < M) {
        int n = nidx[m];
        if (atomicExch(&mark[n], 1) == 0) list[atomicAdd(nmarked, 1)] = n;
    }
}

// ---------------- conversions ----------------

__global__ void k_tobf16(const float* __restrict__ in, unsigned short* __restrict__ out, int n4) {
    int i = blockIdx.x * blockDim.x + threadIdx.x;
    int stride = gridDim.x * blockDim.x;
    for (; i < n4; i += stride) {
        float4 v = ((const float4*)in)[i];
        ushort4 u;
        u.x = f2b(v.x); u.y = f2b(v.y); u.z = f2b(v.z); u.w = f2b(v.w);
        ((ushort4*)out)[i] = u;
    }
}

// offsets: W1l 0, W1r 16384, W2l 32768, W2r 49152, fcW1 65536, fcW2 81920 (total 90112)
__global__ void k_wconv(const float* __restrict__ W1l, const float* __restrict__ W1r,
                        const float* __restrict__ W2l, const float* __restrict__ W2r,
                        const float* __restrict__ fcW1, const float* __restrict__ fcW2,
                        unsigned short* __restrict__ Wb) {
    int i = blockIdx.x * blockDim.x + threadIdx.x;
    if (i >= 90112) return;
    float v;
    if (i < 16384) v = W1l[i];
    else if (i < 32768) v = W1r[i - 16384];
    else if (i < 49152) v = W2l[i - 32768];
    else if (i < 65536) v = W2r[i - 49152];
    else if (i < 81920) v = fcW1[i - 65536];
    else v = fcW2[i - 81920];
    Wb[i] = f2b(v);
}

// ---------------- aggregation: 16-lane-group dwordx4 chain walk ----------------
// wave handles 4 chains; lane group g=lane>>4 owns chain g; lane r=lane&15 owns
// bytes [16r,16r+16) of the row. One dwordx4 instr gathers 4 full rows.
__global__ void k_aggr_g(const int* __restrict__ head, const int2* __restrict__ pk,
                         const uint4* __restrict__ feat,
                         const int* __restrict__ list, const int* __restrict__ nlist,
                         uint4* __restrict__ outf, int n) {
    int lane = threadIdx.x & 63;
    int g = lane >> 4;
    int r = lane & 15;
    int w = blockIdx.x * (blockDim.x >> 6) + (threadIdx.x >> 6);
    int limit = list ? *nlist : n;
    int idx = w * 4 + g;
    int node = (idx < limit) ? (list ? list[idx] : idx) : -1;
    int e = (node >= 0) ? head[node] : -1;
    int2 p = pk[e >= 0 ? e : 0];
    float a[8];
#pragma unroll
    for (int i = 0; i < 8; i++) a[i] = 0.f;
    int cnt = 0;

    while (__any(e >= 0)) {
        int srcn = (e >= 0) ? p.y : 0;
        uint4 u = feat[(size_t)srcn * 16 + r];       // 64 lanes -> 4 rows, 1 instr
        int en = (e >= 0 && p.x >= 0) ? p.x : 0;
        int2 pn = pk[en];                            // next-step pk, 4 addrs/wave
        bool act = e >= 0;
        float m = act ? 1.0f : 0.0f;
        a[0] += m * __uint_as_float(u.x << 16);
        a[1] += m * __uint_as_float(u.x & 0xffff0000u);
        a[2] += m * __uint_as_float(u.y << 16);
        a[3] += m * __uint_as_float(u.y & 0xffff0000u);
        a[4] += m * __uint_as_float(u.z << 16);
        a[5] += m * __uint_as_float(u.z & 0xffff0000u);
        a[6] += m * __uint_as_float(u.w << 16);
        a[7] += m * __uint_as_float(u.w & 0xffff0000u);
        cnt += act ? 1 : 0;
        e = act ? p.x : -1;
        p = pn;
    }
    if (node >= 0) {
        float ic = 1.0f / fmaxf((float)cnt, 1.0f);
        uint4 o;
        o.x = ((unsigned)f2b(a[1] * ic) << 16) | (unsigned)f2b(a[0] * ic);
        o.y = ((unsigned)f2b(a[3] * ic) << 16) | (unsigned)f2b(a[2] * ic);
        o.z = ((unsigned)f2b(a[5] * ic) << 16) | (unsigned)f2b(a[4] * ic);
        o.w = ((unsigned)f2b(a[7] * ic) << 16) | (unsigned)f2b(a[6] * ic);
        outf[(size_t)node * 16 + r] = o;
    }
}

// ---------------- MFMA dense: out = A@Wl.T (+ X@Wr.T) + b ----------------
template <int NCT, int TWO, int RELU, int OUTBF>
__global__ void k_mdense(const unsigned short* __restrict__ A,
                         const unsigned short* __restrict__ X,
                         const int* __restrict__ gidx,
                         const unsigned short* __restrict__ Wl,
                         const float* __restrict__ bl,
                         const unsigned short* __restrict__ Wr,
                         void* __restrict__ outp, int nrows) {
    const int OC = NCT * 16;
    int lane = threadIdx.x & 63;
    int wave = threadIdx.x >> 6;
    int rowBase = (blockIdx.x * 4 + wave) * 32;
    if (rowBase >= nrows) return;
    int rl = lane & 15;
    int ks = lane >> 4;
    int r0 = rowBase + rl, r1 = r0 + 16;
    int n0 = gidx ? gidx[r0] : r0;
    int n1 = gidx ? gidx[r1] : r1;
    f32x4 acc0[NCT], acc1[NCT];
#pragma unroll
    for (int ct = 0; ct < NCT; ct++) {
        acc0[ct] = (f32x4)0.f;
        acc1[ct] = (f32x4)0.f;
    }
#pragma unroll
    for (int pass = 0; pass < (TWO ? 2 : 1); pass++) {
        const unsigned short* Ain = pass ? X : A;
        const unsigned short* W = pass ? Wr : Wl;
        const s16x8* a0p = (const s16x8*)(Ain + (size_t)n0 * 128);
        const s16x8* a1p = (const s16x8*)(Ain + (size_t)n1 * 128);
#pragma unroll
        for (int kc = 0; kc < 4; kc++) {
            s16x8 af0 = a0p[kc * 4 + ks];
            s16x8 af1 = a1p[kc * 4 + ks];
#pragma unroll
            for (int ct = 0; ct < NCT; ct++) {
                const s16x8* bp = (const s16x8*)(W + (size_t)(ct * 16 + rl) * 128);
                s16x8 bf = bp[kc * 4 + ks];
                acc0[ct] = __builtin_amdgcn_mfma_f32_16x16x32_bf16(af0, bf, acc0[ct], 0, 0, 0);
                acc1[ct] = __builtin_amdgcn_mfma_f32_16x16x32_bf16(af1, bf, acc1[ct], 0, 0, 0);
            }
        }
    }
#pragma unroll
    for (int ct = 0; ct < NCT; ct++) {
        int col = ct * 16 + rl;
        float bj = bl[col];
#pragma unroll
        for (int j = 0; j < 4; j++) {
            int or0 = rowBase + ks * 4 + j;
            int or1 = or0 + 16;
            float v0 = acc0[ct][j] + bj;
            float v1 = acc1[ct][j] + bj;
            if (RELU) { v0 = fmaxf(v0, 0.f); v1 = fmaxf(v1, 0.f); }
            if (OUTBF) {
                ((unsigned short*)outp)[(size_t)or0 * OC + col] = f2b(v0);
                ((unsigned short*)outp)[(size_t)or1 * OC + col] = f2b(v1);
            } else {
                ((float*)outp)[(size_t)or0 * OC + col] = v0;
                ((float*)outp)[(size_t)or1 * OC + col] = v1;
            }
        }
    }
}

// ---------------- batchnorm ----------------
template <int C>
__global__ void k_bnstats(const float* __restrict__ z, float* __restrict__ gsum,
                          float* __restrict__ gsq, int nrows, int rowsPerBlock) {
    int t = threadIdx.x;
    int c = t % C;
    int g = t / C;
    const int G = 256 / C;
    int r0 = blockIdx.x * rowsPerBlock;
    int r1 = min(r0 + rowsPerBlock, nrows);
    float s = 0.f, q = 0.f;
    for (int r = r0 + g; r < r1; r += G) {
        float v = z[(size_t)r * C + c];
        s += v;
        q += v * v;
    }
    __shared__ float ls[256], lq[256];
    ls[t] = s;
    lq[t] = q;
    __syncthreads();
    if (t < C) {
        for (int g2 = 1; g2 < G; g2++) {
            s += ls[g2 * C + c];
            q += lq[g2 * C + c];
        }
        atomicAdd(&gsum[c], s);
        atomicAdd(&gsq[c], q);
    }
}

__global__ void k_bnprep(const float* __restrict__ gsum, const float* __restrict__ gsq,
                         const float* __restrict__ gamma, const float* __restrict__ beta,
                         float* __restrict__ scale, float* __restrict__ shift, int C, float invM) {
    int c = blockIdx.x * blockDim.x + threadIdx.x;
    if (c < C) {
        float mean = gsum[c] * invM;
        float var = gsq[c] * invM - mean * mean;
        float is = rsqrtf(var + EPSV);
        float sc = gamma[c] * is;
        scale[c] = sc;
        shift[c] = beta[c] - mean * sc;
    }
}

template <int OUTBF>
__global__ void k_bn_act(const float* __restrict__ z, const float* __restrict__ scale,
                         const float* __restrict__ shift, void* __restrict__ outp,
                         int total, int colsMask, float slope) {
    int i = blockIdx.x * blockDim.x + threadIdx.x;
    if (i < total) {
        int c = i & colsMask;
        float y = z[i] * scale[c] + shift[c];
        y = (y >= 0.f) ? y : slope * y;
        if (OUTBF) ((unsigned short*)outp)[i] = f2b(y);
        else ((float*)outp)[i] = y;
    }
}

// ---------------- final fc3 ----------------
__global__ void k_fc3(const float* __restrict__ z2, const float* __restrict__ w,
                      const float* __restrict__ b, float* __restrict__ out, int nrows) {
    int lane = threadIdx.x & 63;
    int m = blockIdx.x * (blockDim.x >> 6) + (threadIdx.x >> 6);
    if (m >= nrows) return;
    float v = z2[(size_t)m * 64 + lane] * w[lane];
    for (int off = 32; off > 0; off >>= 1) v += __shfl_down(v, off);
    if (lane == 0) out[m] = v + b[0];
}

// ---------------- launch ----------------
extern "C" void kernel_launch(void* const* d_in, const int* in_sizes, int n_in,
                              void* d_out, int out_size, void* d_ws, size_t ws_size,
                              hipStream_t stream) {
    const float* x    = (const float*)d_in[0];
    const int*   ei   = (const int*)d_in[1];
    const int*   nidx = (const int*)d_in[2];
    const float* W1l  = (const float*)d_in[3];
    const float* b1   = (const float*)d_in[4];
    const float* W1r  = (const float*)d_in[5];
    const float* W2l  = (const float*)d_in[6];
    const float* b2   = (const float*)d_in[7];
    const float* W2r  = (const float*)d_in[8];
    const float* fcW1 = (const float*)d_in[9];
    const float* fcb1 = (const float*)d_in[10];
    const float* fcW2 = (const float*)d_in[11];
    const float* fcb2 = (const float*)d_in[12];
    const float* fcW3 = (const float*)d_in[13];
    const float* fcb3 = (const float*)d_in[14];
    const float* g1   = (const float*)d_in[15];
    const float* be1  = (const float*)d_in[16];
    const float* g2   = (const float*)d_in[17];
    const float* be2  = (const float*)d_in[18];

    const int N = in_sizes[0] / 128;
    const int E = in_sizes[1] / 2;
    const int M = in_sizes[2];
    const int* src = ei;
    const int* dst = ei + E;

    char* ws = (char*)d_ws;
    size_t off = 0;
    unsigned short* xb  = (unsigned short*)(ws + off); off += (size_t)N * 128 * 2;
    unsigned short* sb  = (unsigned short*)(ws + off); off += (size_t)N * 128 * 2;
    unsigned short* h1b = (unsigned short*)(ws + off); off += (size_t)N * 128 * 2;
    unsigned short* z0b = (unsigned short*)(ws + off); off += (size_t)M * 128 * 2;
    float* z1           = (float*)(ws + off);          off += (size_t)M * 128 * 4;
    unsigned short* z1b = (unsigned short*)(ws + off); off += (size_t)M * 128 * 2;
    float* z2           = (float*)(ws + off);          off += (size_t)M * 64 * 4;
    unsigned short* Wb  = (unsigned short*)(ws + off); off += 90112 * 2;
    int2* pk       = (int2*)(ws + off);  off += (size_t)E * 8;
    int*  head     = (int*)(ws + off);   off += (size_t)N * 4;
    int*  mark     = (int*)(ws + off);   off += (size_t)N * 4;
    int*  list     = (int*)(ws + off);   off += (size_t)M * 4;
    int*  nmarked  = (int*)(ws + off);   off += 64;
    float* gsum1   = (float*)(ws + off); off += 128 * 4;
    float* gsq1    = (float*)(ws + off); off += 128 * 4;
    float* scale1  = (float*)(ws + off); off += 128 * 4;
    float* shift1  = (float*)(ws + off); off += 128 * 4;
    float* gsum2   = (float*)(ws + off); off += 64 * 4;
    float* gsq2    = (float*)(ws + off); off += 64 * 4;
    float* scale2  = (float*)(ws + off); off += 64 * 4;
    float* shift2  = (float*)(ws + off); off += 64 * 4;
    float* out = (float*)d_out;

    hipMemsetAsync(head, 0xFF, (size_t)N * 4, stream);   // head = -1
    hipMemsetAsync(mark, 0, (size_t)N * 4, stream);
    hipMemsetAsync(nmarked, 0, 4, stream);
    hipMemsetAsync(gsum1, 0, (128 + 128 + 128 + 128 + 64 + 64 + 64 + 64) * 4, stream);

    // conversions (independent of graph build)
    k_wconv<<<(90112 + 255) / 256, 256, 0, stream>>>(W1l, W1r, W2l, W2r, fcW1, fcW2, Wb);
    k_tobf16<<<2048, 256, 0, stream>>>(x, xb, N * 128 / 4);

    // graph build: per-node linked lists
    k_link<<<(E + 255) / 256, 256, 0, stream>>>(src, dst, head, pk, E);
    k_mark<<<(M + 255) / 256, 256, 0, stream>>>(nidx, mark, list, nmarked, M);

    // layer 1: aggregate all nodes
    {
        int waves = (N + 3) / 4;
        k_aggr_g<<<(waves + 3) / 4, 256, 0, stream>>>(
            head, pk, (const uint4*)xb, nullptr, nullptr, (uint4*)sb, N);
    }
    k_mdense<8, 1, 1, 1><<<(N / 32 + 3) / 4, 256, 0, stream>>>(
        sb, xb, nullptr, Wb + 0, b1, Wb + 16384, h1b, N);

    // layer 2: aggregate only marked dst nodes
    {
        int waves = (M + 3) / 4;
        k_aggr_g<<<(waves + 3) / 4, 256, 0, stream>>>(
            head, pk, (const uint4*)h1b, list, nmarked, (uint4*)sb, N);
    }
    k_mdense<8, 1, 0, 1><<<(M / 32 + 3) / 4, 256, 0, stream>>>(
        sb, h1b, nidx, Wb + 32768, b2, Wb + 49152, z0b, M);

    // MLP head
    k_mdense<8, 0, 0, 0><<<(M / 32 + 3) / 4, 256, 0, stream>>>(
        z0b, nullptr, nullptr, Wb + 65536, fcb1, nullptr, z1, M);
    k_bnstats<128><<<(M + 99) / 100, 256, 0, stream>>>(z1, gsum1, gsq1, M, 100);
    k_bnprep<<<1, 128, 0, stream>>>(gsum1, gsq1, g1, be1, scale1, shift1, 128, 1.0f / M);
    k_bn_act<1><<<((size_t)M * 128 + 255) / 256, 256, 0, stream>>>(
        z1, scale1, shift1, z1b, M * 128, 127, 0.1f);

    k_mdense<4, 0, 0, 0><<<(M / 32 + 3) / 4, 256, 0, stream>>>(
        z1b, nullptr, nullptr, Wb + 81920, fcb2, nullptr, z2, M);
    k_bnstats<64><<<(M + 99) / 100, 256, 0, stream>>>(z2, gsum2, gsq2, M, 100);
    k_bnprep<<<1, 64, 0, stream>>>(gsum2, gsq2, g2, be2, scale2, shift2, 64, 1.0f / M);
    k_bn_act<0><<<((size_t)M * 64 + 255) / 256, 256, 0, stream>>>(
        z2, scale2, shift2, z2, M * 64, 63, 0.05f);

    k_fc3<<<(M + 3) / 4, 256, 0, stream>>>(z2, fcW3, fcb3, out, M);
}